// Round 15
// baseline (163.572 us; speedup 1.0000x reference)
//
#include <hip/hip_runtime.h>
#include <hip/hip_bf16.h>

// AttentionHeadRankFour: B=8, X=8, S=1024, D_IN=512, D_OUT=64
// out = softmax_causal( (Xq Wq)(Xk Wk)^T / sqrt(S) ) (Xv Wv)
//
// Pass 0: wprep -> bf16 fragment-ordered W (q_w pre-scaled by log2e/32).
// Pass 1: proj (frozen): LDS-staged GEMM + non-temporal A loads (~83 us).
// Pass 2: attn v8 — v7 shape + software pipeline: static K-register prefetch
//         (kA/kB), double-buffered P in LDS, all explicit fences removed.

typedef short  short8 __attribute__((ext_vector_type(8)));
typedef float  f32x4  __attribute__((ext_vector_type(4)));

#define DIN   512
#define DOUT  64
#define SEQ   1024
#define NROWS 65536   // 8*8*1024

__device__ __forceinline__ unsigned short f2bf(float f) {
    unsigned int u = __float_as_uint(f);
    u += 0x7FFF + ((u >> 16) & 1);   // RNE
    return (unsigned short)(u >> 16);
}

__device__ __forceinline__ unsigned short f2bf_rhu(float f) {   // round-half-up (cheap)
    return (unsigned short)((__float_as_uint(f) + 0x8000u) >> 16);
}

__device__ __forceinline__ float fast_exp2(float x) {
    float r;
    asm("v_exp_f32 %0, %1" : "=v"(r) : "v"(x));
    return r;
}

// ---------------------------------------------------------------------------
// Weight prep: grid (16,3), 256 thr. Wfrag[mode][kk][nt][lane][8] bf16,
// element = W[kk*32 + lg*8 + j][nt*16 + lr]; mode 2 pre-scaled by log2e/32.
// ---------------------------------------------------------------------------
__global__ __launch_bounds__(256)
void wprep_kernel(const float* __restrict__ k_w, const float* __restrict__ v_w,
                  const float* __restrict__ q_w, unsigned short* __restrict__ Wfrag)
{
    const int mode = blockIdx.y;
    const float* w = (mode == 0) ? k_w : (mode == 1) ? v_w : q_w;
    const float sc = (mode == 2) ? 0.0450842200277801f : 1.0f;  // log2(e)/32
    unsigned short* outp = Wfrag + (size_t)mode * 32768;

    const int s  = blockIdx.x * 256 + threadIdx.x;   // (kk,nt,lane) slot
    const int l  = s & 63;
    const int nt = (s >> 6) & 3;
    const int kk = s >> 8;
    const int lr = l & 15, lg = l >> 4;
    short8 frag;
    #pragma unroll
    for (int j = 0; j < 8; ++j)
        frag[j] = (short)f2bf(w[(kk * 32 + lg * 8 + j) * 64 + nt * 16 + lr] * sc);
    *(short8*)&outp[(size_t)s * 8] = frag;
}

// ---------------------------------------------------------------------------
// proj (frozen). Grid (512, 3), 512 thr = 8 waves. Block: 128 rows x K=512.
// Non-temporal coalesced A loads -> f2bf -> XOR-swizzled LDS double buffer.
// ---------------------------------------------------------------------------
__global__ __launch_bounds__(512, 2)
void proj_kernel(const float* __restrict__ k_in, const float* __restrict__ v_in,
                 const float* __restrict__ q_in,
                 const unsigned short* __restrict__ Wfrag,
                 unsigned short* __restrict__ Kb, unsigned short* __restrict__ Vt,
                 unsigned short* __restrict__ Qb)
{
    const int mode = blockIdx.y;
    const float* in = (mode == 0) ? k_in : (mode == 1) ? v_in : q_in;
    const unsigned short* wf = Wfrag + (size_t)mode * 32768;

    __shared__ __align__(16) unsigned short Wlds[32768];       // 64 KB
    __shared__ __align__(16) unsigned short Alds[2][16384];    // 2 x 32 KB

    const int tid = threadIdx.x;
    const int wid = tid >> 6;
    const int l   = tid & 63;
    const int lr  = l & 15;
    const int lg  = l >> 4;
    const int r0  = blockIdx.x * 128;

    const int srow = tid >> 5;
    const int scol = tid & 31;
    const float* sbase = in + (size_t)(r0 + srow) * DIN + scol * 4;

    f32x4 rA[8], rB[8];

    #define LOADC(r, c)                                                        \
        { _Pragma("unroll")                                                    \
          for (int i = 0; i < 8; ++i)                                          \
              r[i] = __builtin_nontemporal_load(                               \
                  (const f32x4*)(sbase + (size_t)i * 16 * DIN + (c) * 128)); }

    #define WRITEC(buf, r)                                                     \
        { _Pragma("unroll")                                                    \
          for (int i = 0; i < 8; ++i) {                                        \
              const int row = srow + i * 16;                                   \
              ushort4 pk;                                                      \
              pk.x = f2bf(r[i].x); pk.y = f2bf(r[i].y);                        \
              pk.z = f2bf(r[i].z); pk.w = f2bf(r[i].w);                        \
              *(ushort4*)((char*)&Alds[buf][0] +                               \
                  ((row * 256 + scol * 8) ^ ((row & 7) << 4))) = pk;           \
          } }

    const int arow  = wid * 16 + lr;
    const int abase = arow * 256 + lg * 16;     // byte offset, + kk*64
    const int aswz  = (arow & 7) << 4;

    f32x4 acc[4];
    #pragma unroll
    for (int nt = 0; nt < 4; ++nt)
        #pragma unroll
        for (int i = 0; i < 4; ++i) acc[nt][i] = 0.f;

    #define COMPUTEC(buf, c)                                                   \
        { _Pragma("unroll")                                                    \
          for (int k = 0; k < 4; ++k) {                                        \
              const short8 af = *(const short8*)((const char*)&Alds[buf][0] +  \
                                  ((abase + k * 64) ^ aswz));                  \
              const int kk = (c) * 4 + k;                                      \
              _Pragma("unroll")                                                \
              for (int nt = 0; nt < 4; ++nt) {                                 \
                  const short8 bf = *(const short8*)&Wlds[((kk * 4 + nt) * 64 + l) * 8]; \
                  acc[nt] = __builtin_amdgcn_mfma_f32_16x16x32_bf16(af, bf, acc[nt], 0, 0, 0); \
              }                                                                \
          } }

    LOADC(rA, 0);
    LOADC(rB, 1);
    #pragma unroll
    for (int i = 0; i < 8; ++i)
        *(short8*)&Wlds[(i * 512 + tid) * 8] = *(const short8*)&wf[(size_t)(i * 512 + tid) * 8];
    WRITEC(0, rA);
    __syncthreads();

    // c=0
    LOADC(rA, 2);
    WRITEC(1, rB);
    COMPUTEC(0, 0);
    __syncthreads();
    // c=1
    LOADC(rB, 3);
    WRITEC(0, rA);
    COMPUTEC(1, 1);
    __syncthreads();
    // c=2
    WRITEC(1, rB);
    COMPUTEC(0, 2);
    __syncthreads();
    // c=3
    COMPUTEC(1, 3);

    if (mode == 1) {
        const int grow = r0 + wid * 16 + lg * 4;
        const int bx = grow >> 10, s = grow & 1023;
        #pragma unroll
        for (int nt = 0; nt < 4; ++nt) {
            ushort4 pk;
            pk.x = f2bf(acc[nt][0]); pk.y = f2bf(acc[nt][1]);
            pk.z = f2bf(acc[nt][2]); pk.w = f2bf(acc[nt][3]);
            *(ushort4*)&Vt[(size_t)bx * 65536 + (size_t)(nt * 16 + lr) * 1024 + s] = pk;
        }
    } else {
        unsigned short* outp = (mode == 0) ? Kb : Qb;
        const int rbase = r0 + wid * 16 + lg * 4;
        #pragma unroll
        for (int nt = 0; nt < 4; ++nt)
            #pragma unroll
            for (int i = 0; i < 4; ++i)
                outp[(size_t)(rbase + i) * 64 + nt * 16 + lr] = f2bf(acc[nt][i]);
    }
    #undef LOADC
    #undef WRITEC
    #undef COMPUTEC
}

// ---------------------------------------------------------------------------
// attn v8. Grid (64 bx, 16 qblk), 256 thr = 4 waves; wave owns 16 q-rows.
// All waves in a block run exactly qblk+1 chunks (qw0 = qblk*64 + wid*16,
// kb <= qw0 steps of 64 -> qblk+1 iterations, block-uniform).
// Pipeline: K chunk c+1 prefetched into the alternate register set while
// PV(c) runs; P double-buffered in LDS; no explicit fences (compiler
// waitcnts handle RAW; per-wave DS pipe is in-order).
// Fixed-m softmax p = 2^(s-8) (shift-invariant; scores |s|<6 @9sigma).
// ---------------------------------------------------------------------------
__global__ __launch_bounds__(256, 3)
void attn_kernel(const unsigned short* __restrict__ Qb,
                 const unsigned short* __restrict__ Kb,
                 const unsigned short* __restrict__ Vt,
                 float* __restrict__ out)
{
    __shared__ __align__(16) unsigned short Plds[4][2][16][72];  // [wave][buf][q][key]

    const int tid  = threadIdx.x;
    const int wid  = tid >> 6;
    const int l    = tid & 63;
    const int lr   = l & 15;
    const int lg   = l >> 4;
    const int bx   = blockIdx.x;
    const int qblk = 15 - (int)blockIdx.y;       // big blocks first
    const int qw0  = qblk * 64 + wid * 16;

    const unsigned short* Qp = Qb + (size_t)bx * 65536;
    const unsigned short* Kp = Kb + (size_t)bx * 65536;
    const unsigned short* Vp = Vt + (size_t)bx * 65536;   // [d][s]

    const short8 qa0 = *(const short8*)&Qp[(size_t)(qw0 + lr) * 64 + lg * 8];
    const short8 qa1 = *(const short8*)&Qp[(size_t)(qw0 + lr) * 64 + 32 + lg * 8];

    const int qrow = qw0 + lg * 4;   // + i

    float lsum[4] = {0.f, 0.f, 0.f, 0.f};
    f32x4 acc[4];
    #pragma unroll
    for (int dt = 0; dt < 4; ++dt)
        #pragma unroll
        for (int i = 0; i < 4; ++i) acc[dt][i] = 0.f;

    short8 kA[8], kB[8];

    // Load all 4 K-tiles of chunk at kb into reg set (indices compile-time).
    #define LOADK(dst, kb_)                                                    \
        { _Pragma("unroll")                                                    \
          for (int kt = 0; kt < 4; ++kt) {                                     \
              dst[kt * 2]     = *(const short8*)&Kp[(size_t)((kb_) + kt * 16 + lr) * 64 + lg * 8]; \
              dst[kt * 2 + 1] = *(const short8*)&Kp[(size_t)((kb_) + kt * 16 + lr) * 64 + 32 + lg * 8]; \
          } }

    // Scores from reg set -> p -> Plds[wid][pb]; skipped tiles write 0.
    #define SCORES(src, pb, kb_)                                               \
        { _Pragma("unroll")                                                    \
          for (int kt = 0; kt < 4; ++kt) {                                     \
              const int kbase = (kb_) + kt * 16;                               \
              if (kbase <= qw0) {                                              \
                  f32x4 t;                                                     \
                  _Pragma("unroll")                                            \
                  for (int i = 0; i < 4; ++i) t[i] = 0.f;                      \
                  t = __builtin_amdgcn_mfma_f32_16x16x32_bf16(qa0, src[kt * 2],     t, 0, 0, 0); \
                  t = __builtin_amdgcn_mfma_f32_16x16x32_bf16(qa1, src[kt * 2 + 1], t, 0, 0, 0); \
                  const int kcol = kbase + lr;                                 \
                  _Pragma("unroll")                                            \
                  for (int i = 0; i < 4; ++i) {                                \
                      const float p = (kcol <= qrow + i) ? fast_exp2(t[i] - 8.0f) : 0.f; \
                      lsum[i] += p;                                            \
                      Plds[wid][pb][lg * 4 + i][kt * 16 + lr] = f2bf_rhu(p);   \
                  }                                                            \
              } else {                                                         \
                  _Pragma("unroll")                                            \
                  for (int i = 0; i < 4; ++i)                                  \
                      Plds[wid][pb][lg * 4 + i][kt * 16 + lr] = 0;             \
              }                                                                \
          } }

    #define PVSTEP(pb, kb_)                                                    \
        { _Pragma("unroll")                                                    \
          for (int c = 0; c < 2; ++c) {                                        \
              if ((kb_) + c * 32 <= qw0 + 15) {                                \
                  const short8 pa = *(const short8*)&Plds[wid][pb][lr][c * 32 + lg * 8]; \
                  _Pragma("unroll")                                            \
                  for (int dt = 0; dt < 4; ++dt) {                             \
                      const short8 vbd = *(const short8*)                      \
                          &Vp[(size_t)(dt * 16 + lr) * 1024 + (kb_) + c * 32 + lg * 8]; \
                      acc[dt] = __builtin_amdgcn_mfma_f32_16x16x32_bf16(pa, vbd, acc[dt], 0, 0, 0); \
                  }                                                            \
              }                                                                \
          } }

    const int nchunks = qblk + 1;     // block-uniform
    int kb = 0, c = 0;
    LOADK(kA, 0);
    while (true) {
        // even chunk: registers kA, P buffer 0
        SCORES(kA, 0, kb);
        if (c + 1 < nchunks) LOADK(kB, kb + 64);
        PVSTEP(0, kb);
        if (c + 1 >= nchunks) break;
        kb += 64; ++c;

        // odd chunk: registers kB, P buffer 1
        SCORES(kB, 1, kb);
        if (c + 1 < nchunks) LOADK(kA, kb + 64);
        PVSTEP(1, kb);
        if (c + 1 >= nchunks) break;
        kb += 64; ++c;
    }
    #undef LOADK
    #undef SCORES
    #undef PVSTEP

    // ---- epilogue: reduce lsum over the 16 key-lanes, normalize, store ----
    #pragma unroll
    for (int d = 1; d < 16; d <<= 1)
        #pragma unroll
        for (int i = 0; i < 4; ++i) lsum[i] += __shfl_xor(lsum[i], d);

    float inv[4];
    #pragma unroll
    for (int i = 0; i < 4; ++i) inv[i] = 1.0f / lsum[i];

    const size_t orow = (size_t)bx * 1024 + qw0;
    #pragma unroll
    for (int dt = 0; dt < 4; ++dt)
        #pragma unroll
        for (int i = 0; i < 4; ++i)
            out[(orow + lg * 4 + i) * 64 + dt * 16 + lr] = acc[dt][i] * inv[i];
}

extern "C" void kernel_launch(void* const* d_in, const int* in_sizes, int n_in,
                              void* d_out, int out_size, void* d_ws, size_t ws_size,
                              hipStream_t stream) {
    const float* k_in = (const float*)d_in[0];
    const float* v_in = (const float*)d_in[1];
    const float* q_in = (const float*)d_in[2];
    const float* k_w  = (const float*)d_in[3];
    const float* v_w  = (const float*)d_in[4];
    const float* q_w  = (const float*)d_in[5];

    unsigned short* Kb    = (unsigned short*)d_ws;              // [65536][64] bf16
    unsigned short* Vt    = Kb + (size_t)NROWS * 64;            // [64][64][1024] bf16
    unsigned short* Qb    = Vt + (size_t)NROWS * 64;            // [65536][64] bf16 (scale in W)
    unsigned short* Wfrag = Qb + (size_t)NROWS * 64;            // 3 x 32768 bf16 fragments

    wprep_kernel<<<dim3(16, 3), 256, 0, stream>>>(k_w, v_w, q_w, Wfrag);
    proj_kernel<<<dim3(512, 3), 512, 0, stream>>>(
        k_in, v_in, q_in, Wfrag, Kb, Vt, Qb);
    attn_kernel<<<dim3(64, 16), 256, 0, stream>>>(Qb, Kb, Vt, (float*)d_out);
}

// Round 16
// 138.934 us; speedup vs baseline: 1.1773x; 1.1773x over previous
//
#include <hip/hip_runtime.h>
#include <hip/hip_bf16.h>

// AttentionHeadRankFour: B=8, X=8, S=1024, D_IN=512, D_OUT=64
// out = softmax_causal( (Xq Wq)(Xk Wk)^T / sqrt(S) ) (Xv Wv)
//
// Pass 0: wprep -> bf16 fragment-ordered W (q_w pre-scaled by log2e/32).
// Pass 1: proj: LDS-staged GEMM + non-temporal A loads. Mode 1 (values) now
//         writes V in MFMA-FRAGMENT order Vfrag[bx][sg][dt][lane][8] so attn's
//         PV B-operand loads are 1 KB contiguous per wave instruction
//         (old [d][s] layout was a 16-row gather @ 2048-B stride = L2
//         channel camping — the attn latency pole).
// Pass 2: attn v9 — v7 shape (256 thr, KVBLK=64, mfma(Q,K), fixed-m exp2
//         softmax, XCD-aware grid) + fragment-ordered V loads.

typedef short  short8 __attribute__((ext_vector_type(8)));
typedef float  f32x4  __attribute__((ext_vector_type(4)));

#define DIN   512
#define DOUT  64
#define SEQ   1024
#define NROWS 65536   // 8*8*1024

__device__ __forceinline__ unsigned short f2bf(float f) {
    unsigned int u = __float_as_uint(f);
    u += 0x7FFF + ((u >> 16) & 1);   // RNE
    return (unsigned short)(u >> 16);
}

__device__ __forceinline__ unsigned short f2bf_rhu(float f) {   // round-half-up (cheap)
    return (unsigned short)((__float_as_uint(f) + 0x8000u) >> 16);
}

__device__ __forceinline__ float fast_exp2(float x) {
    float r;
    asm("v_exp_f32 %0, %1" : "=v"(r) : "v"(x));
    return r;
}

// ---------------------------------------------------------------------------
// Weight prep: grid (16,3), 256 thr. Wfrag[mode][kk][nt][lane][8] bf16,
// element = W[kk*32 + lg*8 + j][nt*16 + lr]; mode 2 pre-scaled by log2e/32.
// ---------------------------------------------------------------------------
__global__ __launch_bounds__(256)
void wprep_kernel(const float* __restrict__ k_w, const float* __restrict__ v_w,
                  const float* __restrict__ q_w, unsigned short* __restrict__ Wfrag)
{
    const int mode = blockIdx.y;
    const float* w = (mode == 0) ? k_w : (mode == 1) ? v_w : q_w;
    const float sc = (mode == 2) ? 0.0450842200277801f : 1.0f;  // log2(e)/32
    unsigned short* outp = Wfrag + (size_t)mode * 32768;

    const int s  = blockIdx.x * 256 + threadIdx.x;   // (kk,nt,lane) slot
    const int l  = s & 63;
    const int nt = (s >> 6) & 3;
    const int kk = s >> 8;
    const int lr = l & 15, lg = l >> 4;
    short8 frag;
    #pragma unroll
    for (int j = 0; j < 8; ++j)
        frag[j] = (short)f2bf(w[(kk * 32 + lg * 8 + j) * 64 + nt * 16 + lr] * sc);
    *(short8*)&outp[(size_t)s * 8] = frag;
}

// ---------------------------------------------------------------------------
// proj. Grid (512, 3), 512 thr = 8 waves. Block: 128 rows x K=512.
// Non-temporal coalesced A loads -> f2bf -> XOR-swizzled LDS double buffer.
// mode 0: keys -> Kb [row][64]; mode 2: queries -> Qb [row][64];
// mode 1: values -> Vfrag[bx][sg][dt][lane][8] (PV fragment order).
// ---------------------------------------------------------------------------
__global__ __launch_bounds__(512, 2)
void proj_kernel(const float* __restrict__ k_in, const float* __restrict__ v_in,
                 const float* __restrict__ q_in,
                 const unsigned short* __restrict__ Wfrag,
                 unsigned short* __restrict__ Kb, unsigned short* __restrict__ Vf,
                 unsigned short* __restrict__ Qb)
{
    const int mode = blockIdx.y;
    const float* in = (mode == 0) ? k_in : (mode == 1) ? v_in : q_in;
    const unsigned short* wf = Wfrag + (size_t)mode * 32768;

    __shared__ __align__(16) unsigned short Wlds[32768];       // 64 KB
    __shared__ __align__(16) unsigned short Alds[2][16384];    // 2 x 32 KB

    const int tid = threadIdx.x;
    const int wid = tid >> 6;
    const int l   = tid & 63;
    const int lr  = l & 15;
    const int lg  = l >> 4;
    const int r0  = blockIdx.x * 128;

    const int srow = tid >> 5;
    const int scol = tid & 31;
    const float* sbase = in + (size_t)(r0 + srow) * DIN + scol * 4;

    f32x4 rA[8], rB[8];

    #define LOADC(r, c)                                                        \
        { _Pragma("unroll")                                                    \
          for (int i = 0; i < 8; ++i)                                          \
              r[i] = __builtin_nontemporal_load(                               \
                  (const f32x4*)(sbase + (size_t)i * 16 * DIN + (c) * 128)); }

    #define WRITEC(buf, r)                                                     \
        { _Pragma("unroll")                                                    \
          for (int i = 0; i < 8; ++i) {                                        \
              const int row = srow + i * 16;                                   \
              ushort4 pk;                                                      \
              pk.x = f2bf(r[i].x); pk.y = f2bf(r[i].y);                        \
              pk.z = f2bf(r[i].z); pk.w = f2bf(r[i].w);                        \
              *(ushort4*)((char*)&Alds[buf][0] +                               \
                  ((row * 256 + scol * 8) ^ ((row & 7) << 4))) = pk;           \
          } }

    const int arow  = wid * 16 + lr;
    const int abase = arow * 256 + lg * 16;     // byte offset, + kk*64
    const int aswz  = (arow & 7) << 4;

    f32x4 acc[4];
    #pragma unroll
    for (int nt = 0; nt < 4; ++nt)
        #pragma unroll
        for (int i = 0; i < 4; ++i) acc[nt][i] = 0.f;

    #define COMPUTEC(buf, c)                                                   \
        { _Pragma("unroll")                                                    \
          for (int k = 0; k < 4; ++k) {                                        \
              const short8 af = *(const short8*)((const char*)&Alds[buf][0] +  \
                                  ((abase + k * 64) ^ aswz));                  \
              const int kk = (c) * 4 + k;                                      \
              _Pragma("unroll")                                                \
              for (int nt = 0; nt < 4; ++nt) {                                 \
                  const short8 bf = *(const short8*)&Wlds[((kk * 4 + nt) * 64 + l) * 8]; \
                  acc[nt] = __builtin_amdgcn_mfma_f32_16x16x32_bf16(af, bf, acc[nt], 0, 0, 0); \
              }                                                                \
          } }

    LOADC(rA, 0);
    LOADC(rB, 1);
    #pragma unroll
    for (int i = 0; i < 8; ++i)
        *(short8*)&Wlds[(i * 512 + tid) * 8] = *(const short8*)&wf[(size_t)(i * 512 + tid) * 8];
    WRITEC(0, rA);
    __syncthreads();

    // c=0
    LOADC(rA, 2);
    WRITEC(1, rB);
    COMPUTEC(0, 0);
    __syncthreads();
    // c=1
    LOADC(rB, 3);
    WRITEC(0, rA);
    COMPUTEC(1, 1);
    __syncthreads();
    // c=2
    WRITEC(1, rB);
    COMPUTEC(0, 2);
    __syncthreads();
    // c=3
    COMPUTEC(1, 3);

    if (mode == 1) {
        // lane holds acc[nt][i] = V[grow + i][nt*16 + lr].
        // Fragment slot for (s,d): sg=s>>5 (per head), l' = (((s&31)>>3)<<4)|lr,
        // j = s&7. grow = ..+lg*4 => j0 = (lg&1)*4, i stays in the same 8-block.
        const int grow = r0 + wid * 16 + lg * 4;
        const int bx = grow >> 10;
        const int sl = grow & 1023;
        const int sg = sl >> 5;
        const int lp = (((sl & 31) >> 3) << 4) | lr;
        const int j0 = sl & 7;
        #pragma unroll
        for (int nt = 0; nt < 4; ++nt) {
            ushort4 pk;
            pk.x = f2bf(acc[nt][0]); pk.y = f2bf(acc[nt][1]);
            pk.z = f2bf(acc[nt][2]); pk.w = f2bf(acc[nt][3]);
            *(ushort4*)&Vf[(((size_t)bx * 32 + sg) * 4 + nt) * 512 + (size_t)lp * 8 + j0] = pk;
        }
    } else {
        unsigned short* outp = (mode == 0) ? Kb : Qb;
        const int rbase = r0 + wid * 16 + lg * 4;
        #pragma unroll
        for (int nt = 0; nt < 4; ++nt)
            #pragma unroll
            for (int i = 0; i < 4; ++i)
                outp[(size_t)(rbase + i) * 64 + nt * 16 + lr] = f2bf(acc[nt][i]);
    }
    #undef LOADC
    #undef WRITEC
    #undef COMPUTEC
}

// ---------------------------------------------------------------------------
// attn v9. Grid (64 bx, 16 qblk), 256 thr = 4 waves; wave owns 16 q-rows.
// XCD locality: linear id = bx + 64*qblk => XCD = bx%8; each XCD serves 8
// heads from its own L2. qblk = 15 - y => longest blocks first.
// KVBLK=64, t = mfma(Q,K) (C: col=lr=key, row=lg*4+i=query). Fixed-m
// softmax p = 2^(s-8) (shift-invariant; log2-domain scores |s|<6 @9sigma).
// PV B-operands from Vfrag: 1 KB contiguous per wave instruction.
// ---------------------------------------------------------------------------
__global__ __launch_bounds__(256)
void attn_kernel(const unsigned short* __restrict__ Qb,
                 const unsigned short* __restrict__ Kb,
                 const unsigned short* __restrict__ Vf,
                 float* __restrict__ out)
{
    __shared__ __align__(16) unsigned short Plds[4][16][72];  // per-wave P tile, padded

    const int tid  = threadIdx.x;
    const int wid  = tid >> 6;
    const int l    = tid & 63;
    const int lr   = l & 15;
    const int lg   = l >> 4;
    const int bx   = blockIdx.x;
    const int qblk = 15 - (int)blockIdx.y;       // big blocks first
    const int qw0  = qblk * 64 + wid * 16;

    const unsigned short* Qp = Qb + (size_t)bx * 65536;
    const unsigned short* Kp = Kb + (size_t)bx * 65536;
    const unsigned short* Vp = Vf + (size_t)bx * 65536;   // fragment order

    const short8 qa0 = *(const short8*)&Qp[(size_t)(qw0 + lr) * 64 + lg * 8];
    const short8 qa1 = *(const short8*)&Qp[(size_t)(qw0 + lr) * 64 + 32 + lg * 8];

    const int qrow = qw0 + lg * 4;   // + i

    float lsum[4] = {0.f, 0.f, 0.f, 0.f};
    f32x4 acc[4];
    #pragma unroll
    for (int dt = 0; dt < 4; ++dt)
        #pragma unroll
        for (int i = 0; i < 4; ++i) acc[dt][i] = 0.f;

    for (int kb = 0; kb <= qw0; kb += 64) {
        // ---- scores -> p -> LDS: 4 tiles of 16 keys ----
        #pragma unroll
        for (int kt = 0; kt < 4; ++kt) {
            const int kbase = kb + kt * 16;
            if (kbase <= qw0) {                // wave-uniform (both mult of 16)
                const short8 k0 = *(const short8*)&Kp[(size_t)(kbase + lr) * 64 + lg * 8];
                const short8 k1 = *(const short8*)&Kp[(size_t)(kbase + lr) * 64 + 32 + lg * 8];
                f32x4 t;
                #pragma unroll
                for (int i = 0; i < 4; ++i) t[i] = 0.f;
                t = __builtin_amdgcn_mfma_f32_16x16x32_bf16(qa0, k0, t, 0, 0, 0);
                t = __builtin_amdgcn_mfma_f32_16x16x32_bf16(qa1, k1, t, 0, 0, 0);
                const int kcol = kbase + lr;
                #pragma unroll
                for (int i = 0; i < 4; ++i) {
                    const float p = (kcol <= qrow + i) ? fast_exp2(t[i] - 8.0f) : 0.f;
                    lsum[i] += p;
                    Plds[wid][lg * 4 + i][kt * 16 + lr] = f2bf_rhu(p);
                }
            } else {
                #pragma unroll
                for (int i = 0; i < 4; ++i)
                    Plds[wid][lg * 4 + i][kt * 16 + lr] = 0;
            }
        }

        // wave-private LDS write -> read (same wave)
        asm volatile("s_waitcnt lgkmcnt(0)" ::: "memory");
        __builtin_amdgcn_sched_barrier(0);

        // ---- PV: static 2 groups of 32 keys, fragment-ordered V loads ----
        #pragma unroll
        for (int c = 0; c < 2; ++c) {
            if (kb + c * 32 <= qw0 + 15) {     // wave-uniform
                const short8 pa = *(const short8*)&Plds[wid][lr][c * 32 + lg * 8];
                const size_t vbase = ((size_t)((kb >> 5) + c) * 4) * 512;
                #pragma unroll
                for (int dt = 0; dt < 4; ++dt) {
                    const short8 vbd = *(const short8*)
                        &Vp[vbase + (size_t)dt * 512 + (size_t)l * 8];
                    acc[dt] = __builtin_amdgcn_mfma_f32_16x16x32_bf16(pa, vbd, acc[dt], 0, 0, 0);
                }
            }
        }
        asm volatile("s_waitcnt lgkmcnt(0)" ::: "memory");
    }

    // ---- epilogue: reduce lsum over the 16 key-lanes, normalize, store ----
    #pragma unroll
    for (int d = 1; d < 16; d <<= 1)
        #pragma unroll
        for (int i = 0; i < 4; ++i) lsum[i] += __shfl_xor(lsum[i], d);

    float inv[4];
    #pragma unroll
    for (int i = 0; i < 4; ++i) inv[i] = 1.0f / lsum[i];

    const size_t orow = (size_t)bx * 1024 + qw0;
    #pragma unroll
    for (int dt = 0; dt < 4; ++dt)
        #pragma unroll
        for (int i = 0; i < 4; ++i)
            out[(orow + lg * 4 + i) * 64 + dt * 16 + lr] = acc[dt][i] * inv[i];
}

extern "C" void kernel_launch(void* const* d_in, const int* in_sizes, int n_in,
                              void* d_out, int out_size, void* d_ws, size_t ws_size,
                              hipStream_t stream) {
    const float* k_in = (const float*)d_in[0];
    const float* v_in = (const float*)d_in[1];
    const float* q_in = (const float*)d_in[2];
    const float* k_w  = (const float*)d_in[3];
    const float* v_w  = (const float*)d_in[4];
    const float* q_w  = (const float*)d_in[5];

    unsigned short* Kb    = (unsigned short*)d_ws;              // [65536][64] bf16
    unsigned short* Vf    = Kb + (size_t)NROWS * 64;            // V fragments, 8 MB
    unsigned short* Qb    = Vf + (size_t)NROWS * 64;            // [65536][64] bf16 (scale in W)
    unsigned short* Wfrag = Qb + (size_t)NROWS * 64;            // 3 x 32768 bf16 fragments

    wprep_kernel<<<dim3(16, 3), 256, 0, stream>>>(k_w, v_w, q_w, Wfrag);
    proj_kernel<<<dim3(512, 3), 512, 0, stream>>>(
        k_in, v_in, q_in, Wfrag, Kb, Vf, Qb);
    attn_kernel<<<dim3(64, 16), 256, 0, stream>>>(Qb, Kb, Vf, (float*)d_out);
}